// Round 8
// baseline (2024.695 us; speedup 1.0000x reference)
//
#include <hip/hip_runtime.h>
#include <cstdint>

#define NPOS 32768
#define IND  512
#define HID  512
#define OUTF 256

typedef float v2f __attribute__((ext_vector_type(2)));

// ---------------------------------------------------------------------------
// K0: transpose W2 [256][512] -> w2t [512][256] (pure copy; values exact)
// ---------------------------------------------------------------------------
__global__ __launch_bounds__(256) void k_transpose(const float* __restrict__ W2,
                                                   float* __restrict__ w2t) {
  __shared__ float tile[32][33];
  int x = threadIdx.x & 31, y = threadIdx.x >> 5;  // 32 x 8
  int hb = blockIdx.x * 32, ob = blockIdx.y * 32;
#pragma unroll
  for (int dy = 0; dy < 32; dy += 8)
    tile[y + dy][x] = W2[(size_t)(ob + y + dy) * HID + hb + x];
  __syncthreads();
#pragma unroll
  for (int dy = 0; dy < 32; dy += 8)
    w2t[(size_t)(hb + y + dy) * OUTF + ob + x] = tile[x][y + dy];
}

// ---------------------------------------------------------------------------
// K1: fc1 GEMM, fp32, BIT-EXACT strict-sequential model of the np reference
// (single accumulator, ascending i, separate mul+add, no FMA), fused
// LIF-period epilogue -> kmap[pos][h] = first crossing step k (0 = never).
// UNCHANGED from the passing round-4/5/7 kernel.
// ---------------------------------------------------------------------------
__global__ __launch_bounds__(256) void k_fc1_kmap(const float* __restrict__ X,
                                                  const float* __restrict__ W1,
                                                  const float* __restrict__ b1,
                                                  unsigned char* __restrict__ kmap) {
  __shared__ float As[8][128];
  __shared__ float Bs[8][128];
  const int row0 = blockIdx.x * 128;   // position tile (32768/128 = 256)
  const int col0 = blockIdx.y * 128;   // hidden tile   (512/128 = 4)
  const int t = threadIdx.x;
  const int tm0 = (t & 15) * 8;
  const int tn0 = (t >> 4) * 8;

  float c[8][8];
#pragma unroll
  for (int i = 0; i < 8; ++i)
#pragma unroll
    for (int j = 0; j < 8; ++j) c[i][j] = 0.0f;

  const int sm = t >> 1;          // 0..127
  const int sk = (t & 1) * 4;     // 0 or 4

  for (int kt = 0; kt < IND; kt += 8) {
    float4 va = *(const float4*)(X + (size_t)(row0 + sm) * IND + kt + sk);
    float4 vb = *(const float4*)(W1 + (size_t)(col0 + sm) * IND + kt + sk);
    __syncthreads();   // protect previous iteration's LDS reads
    As[sk + 0][sm] = va.x; As[sk + 1][sm] = va.y;
    As[sk + 2][sm] = va.z; As[sk + 3][sm] = va.w;
    Bs[sk + 0][sm] = vb.x; Bs[sk + 1][sm] = vb.y;
    Bs[sk + 2][sm] = vb.z; Bs[sk + 3][sm] = vb.w;
    __syncthreads();
#pragma unroll
    for (int kk = 0; kk < 8; ++kk) {   // global i = kt + kk, strictly ascending
      float4 a0 = *(const float4*)&As[kk][tm0];
      float4 a1 = *(const float4*)&As[kk][tm0 + 4];
      float4 b0 = *(const float4*)&Bs[kk][tn0];
      float4 b1_ = *(const float4*)&Bs[kk][tn0 + 4];
      float a[8] = {a0.x, a0.y, a0.z, a0.w, a1.x, a1.y, a1.z, a1.w};
      float b[8] = {b0.x, b0.y, b0.z, b0.w, b1_.x, b1_.y, b1_.z, b1_.w};
#pragma unroll
      for (int i = 0; i < 8; ++i)
#pragma unroll
        for (int j = 0; j < 8; ++j)
          c[i][j] = __fadd_rn(c[i][j], __fmul_rn(a[i], b[j]));  // no contraction
    }
  }

  float4 b1a = *(const float4*)(b1 + col0 + tn0);
  float4 b1b = *(const float4*)(b1 + col0 + tn0 + 4);
  float b1v[8] = {b1a.x, b1a.y, b1a.z, b1a.w, b1b.x, b1b.y, b1b.z, b1b.w};

#pragma unroll
  for (int i = 0; i < 8; ++i) {
    unsigned long long pk = 0;
#pragma unroll
    for (int j = 0; j < 8; ++j) {
      float pre = __fadd_rn(c[i][j], b1v[j]);
      float m = 0.0f;
      int kv = 0;
#pragma unroll
      for (int tt = 1; tt <= 16; ++tt) {
        m = __fadd_rn(m, pre);
        if (m > 0.5f && kv == 0) kv = tt;
      }
      pk |= (unsigned long long)(unsigned int)kv << (8 * j);
    }
    *(unsigned long long*)(kmap + (size_t)(row0 + tm0 + i) * HID + col0 + tn0) = pk;
  }
}

// ---------------------------------------------------------------------------
// K2: exact-order fc2 + mem2 sim — LDS-staged W2, volatile pk-add switch.
// Block = 512 threads = 8 waves = 8 positions; lane owns outputs o=4*lane..+3.
// w2t staged in 8 x 64KB chunks (64 h x 256 o fp32), coalesced, shared by all
// 8 waves (kills the per-h L2 latency chain of round 7: LDS ~120cyc + huge BW).
// Per spiking h (k wave-uniform, scalar-decoded): two ds_read_b64 + k-switch
// of volatile v_pk_add_f32 (cannot be speculated -> branches stay real; only
// useful adds execute). Per-o add sequence identical to passing rounds.
// ---------------------------------------------------------------------------
__global__ __launch_bounds__(512) void k_snn_fc2(const unsigned char* __restrict__ kmap,
                                                 const float* __restrict__ w2t,
                                                 const float* __restrict__ b2,
                                                 float* __restrict__ out) {
  __shared__ float w2s[64 * 256];         // 64 KB chunk: [h'][o]
  const int tid = threadIdx.x;
  const int wave = tid >> 6;
  const int lane = tid & 63;              // o = 4*lane + {0,1,2,3}
  const size_t pos = (size_t)blockIdx.x * 8 + wave;

  v2f z = {0.f, 0.f};
  v2f a1l = z, a2l = z, a3l = z, a4l = z, a5l = z, a6l = z, a7l = z, a8l = z,
      a9l = z, a10l = z, a11l = z, a12l = z, a13l = z, a14l = z, a15l = z, a16l = z;
  v2f a1h = z, a2h = z, a3h = z, a4h = z, a5h = z, a6h = z, a7h = z, a8h = z,
      a9h = z, a10h = z, a11h = z, a12h = z, a13h = z, a14h = z, a15h = z, a16h = z;

  const v2f* wp = (const v2f*)w2s;        // pair view of LDS chunk

#define PK2(accl, acch)                                                   \
  do {                                                                    \
    asm volatile("v_pk_add_f32 %0, %0, %1" : "+v"(accl) : "v"(wlo));      \
    asm volatile("v_pk_add_f32 %0, %0, %1" : "+v"(acch) : "v"(whi));      \
  } while (0)

#define DO_H(HL, KB)                                                      \
  do {                                                                    \
    int k_ = (int)(KB);                                                   \
    if (k_) {                                                             \
      v2f wlo = wp[(HL) * 128 + lane * 2];                                \
      v2f whi = wp[(HL) * 128 + lane * 2 + 1];                            \
      switch (k_) {                                                       \
        case 1:                                                           \
          PK2(a1l, a1h);  PK2(a2l, a2h);  PK2(a3l, a3h);  PK2(a4l, a4h);  \
          PK2(a5l, a5h);  PK2(a6l, a6h);  PK2(a7l, a7h);  PK2(a8l, a8h);  \
          PK2(a9l, a9h);  PK2(a10l, a10h); PK2(a11l, a11h); PK2(a12l, a12h);\
          PK2(a13l, a13h); PK2(a14l, a14h); PK2(a15l, a15h); PK2(a16l, a16h);\
          break;                                                          \
        case 2:                                                           \
          PK2(a2l, a2h);  PK2(a4l, a4h);  PK2(a6l, a6h);  PK2(a8l, a8h);  \
          PK2(a10l, a10h); PK2(a12l, a12h); PK2(a14l, a14h); PK2(a16l, a16h);\
          break;                                                          \
        case 3:                                                           \
          PK2(a3l, a3h); PK2(a6l, a6h); PK2(a9l, a9h); PK2(a12l, a12h);   \
          PK2(a15l, a15h); break;                                         \
        case 4:                                                           \
          PK2(a4l, a4h); PK2(a8l, a8h); PK2(a12l, a12h); PK2(a16l, a16h); \
          break;                                                          \
        case 5:  PK2(a5l, a5h); PK2(a10l, a10h); PK2(a15l, a15h); break;  \
        case 6:  PK2(a6l, a6h); PK2(a12l, a12h); break;                   \
        case 7:  PK2(a7l, a7h); PK2(a14l, a14h); break;                   \
        case 8:  PK2(a8l, a8h); PK2(a16l, a16h); break;                   \
        case 9:  PK2(a9l, a9h); break;                                    \
        case 10: PK2(a10l, a10h); break;                                  \
        case 11: PK2(a11l, a11h); break;                                  \
        case 12: PK2(a12l, a12h); break;                                  \
        case 13: PK2(a13l, a13h); break;                                  \
        case 14: PK2(a14l, a14h); break;                                  \
        case 15: PK2(a15l, a15h); break;                                  \
        default: PK2(a16l, a16h); break;  /* k == 16 */                   \
      }                                                                   \
    }                                                                     \
  } while (0)

  for (int ch = 0; ch < 8; ++ch) {
    __syncthreads();                      // protect previous chunk's reads
    const float4* src = (const float4*)(w2t + (size_t)ch * 64 * 256);
#pragma unroll
    for (int j = 0; j < 8; ++j) {         // 4096 float4 per chunk / 512 thr
      int fi = tid + j * 512;
      ((float4*)w2s)[fi] = src[fi];
    }
    __syncthreads();

    const uint4* kp = (const uint4*)(kmap + pos * HID + ch * 64);
#pragma unroll
    for (int q = 0; q < 4; ++q) {         // 16 h per uint4
      uint4 kw = kp[q];                   // wave-uniform address
      int hl = q * 16;
      {
        unsigned uw = __builtin_amdgcn_readfirstlane(kw.x);
        DO_H(hl + 0, uw & 255u);         DO_H(hl + 1, (uw >> 8) & 255u);
        DO_H(hl + 2, (uw >> 16) & 255u); DO_H(hl + 3, uw >> 24);
      }
      {
        unsigned uw = __builtin_amdgcn_readfirstlane(kw.y);
        DO_H(hl + 4, uw & 255u);         DO_H(hl + 5, (uw >> 8) & 255u);
        DO_H(hl + 6, (uw >> 16) & 255u); DO_H(hl + 7, uw >> 24);
      }
      {
        unsigned uw = __builtin_amdgcn_readfirstlane(kw.z);
        DO_H(hl + 8, uw & 255u);          DO_H(hl + 9, (uw >> 8) & 255u);
        DO_H(hl + 10, (uw >> 16) & 255u); DO_H(hl + 11, uw >> 24);
      }
      {
        unsigned uw = __builtin_amdgcn_readfirstlane(kw.w);
        DO_H(hl + 12, uw & 255u);         DO_H(hl + 13, (uw >> 8) & 255u);
        DO_H(hl + 14, (uw >> 16) & 255u); DO_H(hl + 15, uw >> 24);
      }
    }
  }
#undef DO_H
#undef PK2

  // mem2 simulation, exact fp32 per output: mem = (mem + c_t) + b2; spike.
  float4 b2v = *(const float4*)(b2 + 4 * lane);
  float m0 = 0.f, m1 = 0.f, m2 = 0.f, m3 = 0.f;
  float s0 = 0.f, s1 = 0.f, s2 = 0.f, s3 = 0.f;
#define STEP(AL, AH)                                          \
  do {                                                        \
    m0 = __fadd_rn(__fadd_rn(m0, (AL).x), b2v.x);             \
    if (m0 > 0.5f) { s0 += 1.0f; m0 = 0.0f; }                 \
    m1 = __fadd_rn(__fadd_rn(m1, (AL).y), b2v.y);             \
    if (m1 > 0.5f) { s1 += 1.0f; m1 = 0.0f; }                 \
    m2 = __fadd_rn(__fadd_rn(m2, (AH).x), b2v.z);             \
    if (m2 > 0.5f) { s2 += 1.0f; m2 = 0.0f; }                 \
    m3 = __fadd_rn(__fadd_rn(m3, (AH).y), b2v.w);             \
    if (m3 > 0.5f) { s3 += 1.0f; m3 = 0.0f; }                 \
  } while (0)
  STEP(a1l, a1h);   STEP(a2l, a2h);   STEP(a3l, a3h);   STEP(a4l, a4h);
  STEP(a5l, a5h);   STEP(a6l, a6h);   STEP(a7l, a7h);   STEP(a8l, a8h);
  STEP(a9l, a9h);   STEP(a10l, a10h); STEP(a11l, a11h); STEP(a12l, a12h);
  STEP(a13l, a13h); STEP(a14l, a14h); STEP(a15l, a15h); STEP(a16l, a16h);
#undef STEP
  float4 r = make_float4(s0 * 0.0625f, s1 * 0.0625f, s2 * 0.0625f, s3 * 0.0625f);
  *(float4*)(out + pos * OUTF + 4 * lane) = r;
}

// ---------------------------------------------------------------------------
extern "C" void kernel_launch(void* const* d_in, const int* in_sizes, int n_in,
                              void* d_out, int out_size, void* d_ws, size_t ws_size,
                              hipStream_t stream) {
  const float* X  = (const float*)d_in[0];   // [16,2048,512]
  const float* W1 = (const float*)d_in[1];   // [512,512]
  const float* b1 = (const float*)d_in[2];   // [512]
  const float* W2 = (const float*)d_in[3];   // [256,512]
  const float* b2 = (const float*)d_in[4];   // [256]
  float* out = (float*)d_out;                // [32768,256]

  float* w2t = (float*)d_ws;                                           // 512 KB
  unsigned char* kmap = (unsigned char*)d_ws + (size_t)HID * OUTF * 4; // 16 MB

  k_transpose<<<dim3(16, 8), 256, 0, stream>>>(W2, w2t);
  k_fc1_kmap<<<dim3(256, 4), 256, 0, stream>>>(X, W1, b1, kmap);
  k_snn_fc2<<<NPOS / 8, 512, 0, stream>>>(kmap, w2t, b2, out);
}